// Round 1
// baseline (1069.897 us; speedup 1.0000x reference)
//
#include <hip/hip_runtime.h>

typedef __bf16 bf16x8 __attribute__((ext_vector_type(8)));
typedef float f32x4 __attribute__((ext_vector_type(4)));
typedef unsigned short ushort8v __attribute__((ext_vector_type(8)));
typedef unsigned short ushort4v __attribute__((ext_vector_type(4)));

#define BATCH 32
#define NBOX 40
#define CCH 256
#define HF 64
#define WF 64
#define RREG 29
#define OUTP 7
#define MROWS 928           // BATCH*RREG
#define DDIM 12544          // CCH*7*7
#define N1DIM 2048
#define FDIM 768

// workspace layout (bytes)
static constexpr size_t OFF_ROIS = 0;                                   // 928*4 f32
static constexpr size_t OFF_DET  = 16384;                               // 928 i32
static constexpr size_t OFF_A    = 32768;                               // bf16 [928][12544]
static constexpr size_t OFF_W1T  = OFF_A   + (size_t)MROWS * DDIM * 2;  // bf16 [2048][12544]
static constexpr size_t OFF_W2T  = OFF_W1T + (size_t)DDIM * N1DIM * 2;  // bf16 [768][2048]
static constexpr size_t OFF_G1   = OFF_W2T + (size_t)N1DIM * FDIM * 2;  // f32 [928][2048]
static constexpr size_t OFF_H    = OFF_G1  + (size_t)MROWS * N1DIM * 4; // bf16 [928][2048]
static constexpr size_t OFF_G2   = OFF_H   + (size_t)MROWS * N1DIM * 2; // f32 [928][768]

static __device__ __forceinline__ unsigned short f2bf(float f) {
  __bf16 h = (__bf16)f;
  return __builtin_bit_cast(unsigned short, h);
}

// ---------------- 1. box selection ----------------
__global__ __launch_bounds__(256) void select_kernel(const float* __restrict__ boxes,
                                                     const float* __restrict__ scores,
                                                     const int* __restrict__ labels,
                                                     float* __restrict__ rois,
                                                     int* __restrict__ det,
                                                     float* __restrict__ out_det) {
  int tid = blockIdx.x * 256 + threadIdx.x;
  if (tid >= MROWS) return;
  int b = tid / RREG, r = tid % RREG;
  float bestS = -1.0f;
  int bestN = 0;
  int found = 0;
  for (int n = 0; n < NBOX; ++n) {
    int lab = labels[b * NBOX + n];
    int ri = min(max(lab, 1), RREG) - 1;
    if (ri == r) {
      found = 1;
      float s = scores[b * NBOX + n];
      if (s > bestS) { bestS = s; bestN = n; }   // first-max semantics (strict >)
    }
  }
  const float scale = 0.0625f;   // min(64/1024, 64/1024)
  float4 bx = *(const float4*)&boxes[(b * NBOX + bestN) * 4];
  rois[tid * 4 + 0] = bx.x * scale;
  rois[tid * 4 + 1] = bx.y * scale;
  rois[tid * 4 + 2] = bx.z * scale;
  rois[tid * 4 + 3] = bx.w * scale;
  det[tid] = found;
  out_det[tid] = found ? 1.0f : 0.0f;
}

// ---------------- 2. roi align -> bf16 flat [928][12544] ----------------
__global__ __launch_bounds__(256) void roi_kernel(const float* __restrict__ fm,
                                                  const float* __restrict__ rois,
                                                  unsigned short* __restrict__ A) {
  __shared__ int4 sidx[196];
  __shared__ float4 sw[196];
  int roi = blockIdx.x;
  int t = threadIdx.x;
  float rx1 = rois[roi * 4 + 0], ry1 = rois[roi * 4 + 1];
  float rx2 = rois[roi * 4 + 2], ry2 = rois[roi * 4 + 3];
  float roiw = fmaxf(rx2 - rx1, 1.f), roih = fmaxf(ry2 - ry1, 1.f);
  float bw = roiw * (1.f / OUTP), bh = roih * (1.f / OUTP);
  if (t < 196) {
    int oy = t / 28, rem = t % 28, ox = rem / 4, s = rem % 4, sy = s >> 1, sx = s & 1;
    float y = ry1 + ((float)oy + ((float)sy + 0.5f) * 0.5f) * bh;
    float x = rx1 + ((float)ox + ((float)sx + 0.5f) * 0.5f) * bw;
    bool valid = (y >= -1.f) && (y <= 64.f) && (x >= -1.f) && (x <= 64.f);
    float yc = fminf(fmaxf(y, 0.f), 63.f);
    float xc = fminf(fmaxf(x, 0.f), 63.f);
    int y0 = (int)floorf(yc), x0 = (int)floorf(xc);
    int y1i = min(y0 + 1, 63), x1i = min(x0 + 1, 63);
    float ly = yc - (float)y0, lx = xc - (float)x0;
    float hy = 1.f - ly, hx = 1.f - lx;
    float m = valid ? 1.f : 0.f;
    sw[t] = make_float4(hy * hx * m, hy * lx * m, ly * hx * m, ly * lx * m);
    sidx[t] = make_int4(y0 * 64 + x0, y0 * 64 + x1i, y1i * 64 + x0, y1i * 64 + x1i);
  }
  __syncthreads();
  int b = roi / RREG;
  const float* base = fm + ((long)b * CCH + t) * (HF * WF);   // t = channel
  long outBase = (long)roi * DDIM + (long)t * 49;
  for (int bin = 0; bin < 49; ++bin) {
    float acc = 0.f;
#pragma unroll
    for (int s = 0; s < 4; ++s) {
      int sid = bin * 4 + s;
      int4 ix = sidx[sid];
      float4 w = sw[sid];
      acc += w.x * base[ix.x] + w.y * base[ix.y] + w.z * base[ix.z] + w.w * base[ix.w];
    }
    A[outBase + bin] = f2bf(acc * 0.25f);
  }
}

// ---------------- 3. transpose f32 [K][N] -> bf16 [N][K] ----------------
__global__ __launch_bounds__(256) void transpose_kernel(const float* __restrict__ in,
                                                        unsigned short* __restrict__ out,
                                                        int K, int N) {
  __shared__ float tile[64][65];
  int k0 = blockIdx.x * 64, n0 = blockIdx.y * 64;
  int t = threadIdx.x, tx = t & 15, ty = t >> 4;
#pragma unroll
  for (int p = 0; p < 4; ++p) {
    int r = ty + p * 16;
    float4 v = *(const float4*)&in[(long)(k0 + r) * N + n0 + tx * 4];
    tile[r][tx * 4 + 0] = v.x;
    tile[r][tx * 4 + 1] = v.y;
    tile[r][tx * 4 + 2] = v.z;
    tile[r][tx * 4 + 3] = v.w;
  }
  __syncthreads();
#pragma unroll
  for (int p = 0; p < 4; ++p) {
    int r = ty + p * 16;
    ushort4v o;
    o[0] = f2bf(tile[tx * 4 + 0][r]);
    o[1] = f2bf(tile[tx * 4 + 1][r]);
    o[2] = f2bf(tile[tx * 4 + 2][r]);
    o[3] = f2bf(tile[tx * 4 + 3][r]);
    *(ushort4v*)&out[(long)(n0 + r) * K + k0 + tx * 4] = o;
  }
}

// ---------------- 4. bf16 MFMA GEMM: C[M][N] = A[M][K] * Bt[N][K]^T ----------------
__global__ __launch_bounds__(256) void gemm_kernel(const unsigned short* __restrict__ A,
                                                   const unsigned short* __restrict__ Bt,
                                                   float* __restrict__ C,
                                                   int M, int N, int K) {
  __shared__ unsigned short As[128][40];   // +8 pad -> 2-way bank aliasing (free)
  __shared__ unsigned short Bs[64][40];
  int t = threadIdx.x;
  int lane = t & 63, wv = t >> 6;
  int wr = wv >> 1, wc = wv & 1;           // wave grid 2x2 over 128x64
  int bm = blockIdx.x, bn = blockIdx.y;
  f32x4 acc[4][2];
#pragma unroll
  for (int m = 0; m < 4; ++m)
#pragma unroll
    for (int n = 0; n < 2; ++n) acc[m][n] = (f32x4){0.f, 0.f, 0.f, 0.f};

  int arow = t >> 1, ah = t & 1;           // A stage: 2 thr/row, 16 elems each
  long aoff = (long)(bm * 128 + arow) * K + ah * 16;
  bool av = (bm * 128 + arow) < M;
  int brow = t >> 2, bq = t & 3;           // B stage: 4 thr/row, 8 elems each
  long boff = (long)(bn * 64 + brow) * K + bq * 8;
  int fr = lane & 15, kk = (lane >> 4) * 8;

  for (int k0 = 0; k0 < K; k0 += 32) {
    __syncthreads();
    if (av) {
      *(ushort8v*)&As[arow][ah * 16]     = *(const ushort8v*)(A + aoff + k0);
      *(ushort8v*)&As[arow][ah * 16 + 8] = *(const ushort8v*)(A + aoff + k0 + 8);
    } else {
      ushort8v z = {0, 0, 0, 0, 0, 0, 0, 0};
      *(ushort8v*)&As[arow][ah * 16] = z;
      *(ushort8v*)&As[arow][ah * 16 + 8] = z;
    }
    *(ushort8v*)&Bs[brow][bq * 8] = *(const ushort8v*)(Bt + boff + k0);
    __syncthreads();
    bf16x8 af[4], bfr[2];
#pragma unroll
    for (int m = 0; m < 4; ++m) af[m] = *(bf16x8*)&As[wr * 64 + m * 16 + fr][kk];
#pragma unroll
    for (int n = 0; n < 2; ++n) bfr[n] = *(bf16x8*)&Bs[wc * 32 + n * 16 + fr][kk];
#pragma unroll
    for (int m = 0; m < 4; ++m)
#pragma unroll
      for (int n = 0; n < 2; ++n)
        acc[m][n] = __builtin_amdgcn_mfma_f32_16x16x32_bf16(af[m], bfr[n], acc[m][n], 0, 0, 0);
  }

  int fq = lane >> 4;
#pragma unroll
  for (int m = 0; m < 4; ++m)
#pragma unroll
    for (int n = 0; n < 2; ++n) {
      int col = bn * 64 + wc * 32 + n * 16 + fr;
#pragma unroll
      for (int j = 0; j < 4; ++j) {
        int row = bm * 128 + wr * 64 + m * 16 + fq * 4 + j;
        if (row < M) C[(long)row * N + col] = acc[m][n][j];
      }
    }
}

// ---------------- block reduce helper ----------------
static __device__ __forceinline__ void block_reduce2(float& a, float& b, float* sm) {
#pragma unroll
  for (int off = 32; off > 0; off >>= 1) {
    a += __shfl_down(a, off);
    b += __shfl_down(b, off);
  }
  int lane = threadIdx.x & 63, wv = threadIdx.x >> 6;
  if (lane == 0) { sm[wv] = a; sm[wv + 4] = b; }
  __syncthreads();
  a = sm[0] + sm[1] + sm[2] + sm[3];
  b = sm[4] + sm[5] + sm[6] + sm[7];
}

// ---------------- 5. bias + LN + ReLU -> bf16 h ----------------
__global__ __launch_bounds__(256) void ln1_kernel(const float* __restrict__ X,
                                                  const float* __restrict__ b1,
                                                  const float* __restrict__ g1,
                                                  const float* __restrict__ be1,
                                                  unsigned short* __restrict__ H) {
  __shared__ float sm[8];
  int row = blockIdx.x, t = threadIdx.x;
  float x[8];
  float sum = 0.f, sq = 0.f;
#pragma unroll
  for (int i = 0; i < 8; ++i) {
    int j = t + i * 256;
    x[i] = X[(long)row * N1DIM + j] + b1[j];
    sum += x[i];
    sq += x[i] * x[i];
  }
  block_reduce2(sum, sq, sm);
  float mu = sum * (1.f / N1DIM);
  float inv = rsqrtf(sq * (1.f / N1DIM) - mu * mu + 1e-5f);
#pragma unroll
  for (int i = 0; i < 8; ++i) {
    int j = t + i * 256;
    float y = fmaxf((x[i] - mu) * inv * g1[j] + be1[j], 0.f);
    H[(long)row * N1DIM + j] = f2bf(y);
  }
}

// ---------------- 6. bias + LN + missing-token select -> out ----------------
__global__ __launch_bounds__(256) void ln2_kernel(const float* __restrict__ X,
                                                  const float* __restrict__ b2,
                                                  const float* __restrict__ g2,
                                                  const float* __restrict__ be2,
                                                  const float* __restrict__ miss,
                                                  const int* __restrict__ det,
                                                  float* __restrict__ out) {
  __shared__ float sm[8];
  int row = blockIdx.x, t = threadIdx.x;
  float x[3];
  float sum = 0.f, sq = 0.f;
#pragma unroll
  for (int i = 0; i < 3; ++i) {
    int j = t + i * 256;
    x[i] = X[(long)row * FDIM + j] + b2[j];
    sum += x[i];
    sq += x[i] * x[i];
  }
  block_reduce2(sum, sq, sm);
  float mu = sum * (1.f / FDIM);
  float inv = rsqrtf(sq * (1.f / FDIM) - mu * mu + 1e-5f);
  int dv = det[row];
#pragma unroll
  for (int i = 0; i < 3; ++i) {
    int j = t + i * 256;
    float y = (x[i] - mu) * inv * g2[j] + be2[j];
    out[(long)row * FDIM + j] = dv ? y : miss[j];
  }
}

extern "C" void kernel_launch(void* const* d_in, const int* in_sizes, int n_in,
                              void* d_out, int out_size, void* d_ws, size_t ws_size,
                              hipStream_t stream) {
  const float* fm     = (const float*)d_in[0];
  const float* boxes  = (const float*)d_in[1];
  const float* scores = (const float*)d_in[2];
  const int*   labels = (const int*)d_in[3];
  const float* w1     = (const float*)d_in[4];
  const float* b1     = (const float*)d_in[5];
  const float* g1     = (const float*)d_in[6];
  const float* be1    = (const float*)d_in[7];
  const float* w2     = (const float*)d_in[8];
  const float* b2     = (const float*)d_in[9];
  const float* g2     = (const float*)d_in[10];
  const float* be2    = (const float*)d_in[11];
  const float* miss   = (const float*)d_in[12];
  float* out = (float*)d_out;
  char* ws = (char*)d_ws;

  float* rois = (float*)(ws + OFF_ROIS);
  int* det = (int*)(ws + OFF_DET);
  unsigned short* Abf = (unsigned short*)(ws + OFF_A);
  unsigned short* w1t = (unsigned short*)(ws + OFF_W1T);
  unsigned short* w2t = (unsigned short*)(ws + OFF_W2T);
  float* G1 = (float*)(ws + OFF_G1);
  unsigned short* Hbf = (unsigned short*)(ws + OFF_H);
  float* G2 = (float*)(ws + OFF_G2);

  hipLaunchKernelGGL(select_kernel, dim3(4), dim3(256), 0, stream,
                     boxes, scores, labels, rois, det, out + (long)MROWS * FDIM);
  hipLaunchKernelGGL(roi_kernel, dim3(MROWS), dim3(256), 0, stream, fm, rois, Abf);
  hipLaunchKernelGGL(transpose_kernel, dim3(DDIM / 64, N1DIM / 64), dim3(256), 0, stream,
                     w1, w1t, DDIM, N1DIM);
  hipLaunchKernelGGL(transpose_kernel, dim3(N1DIM / 64, FDIM / 64), dim3(256), 0, stream,
                     w2, w2t, N1DIM, FDIM);
  hipLaunchKernelGGL(gemm_kernel, dim3(8, N1DIM / 64), dim3(256), 0, stream,
                     Abf, w1t, G1, MROWS, N1DIM, DDIM);
  hipLaunchKernelGGL(ln1_kernel, dim3(MROWS), dim3(256), 0, stream, G1, b1, g1, be1, Hbf);
  hipLaunchKernelGGL(gemm_kernel, dim3(8, FDIM / 64), dim3(256), 0, stream,
                     Hbf, w2t, G2, MROWS, FDIM, N1DIM);
  hipLaunchKernelGGL(ln2_kernel, dim3(MROWS), dim3(256), 0, stream,
                     G2, b2, g2, be2, miss, det, out);
}

// Round 2
// 467.350 us; speedup vs baseline: 2.2893x; 2.2893x over previous
//
#include <hip/hip_runtime.h>

typedef __bf16 bf16x8 __attribute__((ext_vector_type(8)));
typedef float f32x4 __attribute__((ext_vector_type(4)));
typedef unsigned short ushort8v __attribute__((ext_vector_type(8)));
typedef unsigned short ushort4v __attribute__((ext_vector_type(4)));

#define BATCH 32
#define NBOX 40
#define CCH 256
#define HF 64
#define WF 64
#define RREG 29
#define OUTP 7
#define MROWS 928           // BATCH*RREG
#define DDIM 12544          // CCH*7*7
#define N1DIM 2048
#define FDIM 768
#define PDIM 4096           // HF*WF

// workspace layout (bytes). fmT aliases the W1T..G2 region (dead by then).
static constexpr size_t OFF_ROIS = 0;                                   // 928*4 f32
static constexpr size_t OFF_DET  = 16384;                               // 928 i32
static constexpr size_t OFF_A    = 32768;                               // bf16 [928][12544]
static constexpr size_t OFF_W1T  = OFF_A   + (size_t)MROWS * DDIM * 2;  // bf16 [2048][12544]
static constexpr size_t OFF_FMT  = OFF_W1T;                             // bf16 [32][4096][256] (aliased)
static constexpr size_t OFF_W2T  = OFF_W1T + (size_t)DDIM * N1DIM * 2;  // bf16 [768][2048]
static constexpr size_t OFF_G1   = OFF_W2T + (size_t)N1DIM * FDIM * 2;  // f32 [928][2048]
static constexpr size_t OFF_H    = OFF_G1  + (size_t)MROWS * N1DIM * 4; // bf16 [928][2048]
static constexpr size_t OFF_G2   = OFF_H   + (size_t)MROWS * N1DIM * 2; // f32 [928][768]

static __device__ __forceinline__ unsigned short f2bf(float f) {
  __bf16 h = (__bf16)f;
  return __builtin_bit_cast(unsigned short, h);
}
static __device__ __forceinline__ float bf2f(unsigned short u) {
  unsigned int x = ((unsigned int)u) << 16;
  return __builtin_bit_cast(float, x);
}

// ---------------- 1. box selection ----------------
__global__ __launch_bounds__(256) void select_kernel(const float* __restrict__ boxes,
                                                     const float* __restrict__ scores,
                                                     const int* __restrict__ labels,
                                                     float* __restrict__ rois,
                                                     int* __restrict__ det,
                                                     float* __restrict__ out_det) {
  int tid = blockIdx.x * 256 + threadIdx.x;
  if (tid >= MROWS) return;
  int b = tid / RREG, r = tid % RREG;
  float bestS = -1.0f;
  int bestN = 0;
  int found = 0;
  for (int n = 0; n < NBOX; ++n) {
    int lab = labels[b * NBOX + n];
    int ri = min(max(lab, 1), RREG) - 1;
    if (ri == r) {
      found = 1;
      float s = scores[b * NBOX + n];
      if (s > bestS) { bestS = s; bestN = n; }   // first-max semantics (strict >)
    }
  }
  const float scale = 0.0625f;   // min(64/1024, 64/1024)
  float4 bx = *(const float4*)&boxes[(b * NBOX + bestN) * 4];
  rois[tid * 4 + 0] = bx.x * scale;
  rois[tid * 4 + 1] = bx.y * scale;
  rois[tid * 4 + 2] = bx.z * scale;
  rois[tid * 4 + 3] = bx.w * scale;
  det[tid] = found;
  out_det[tid] = found ? 1.0f : 0.0f;
}

// ---------------- 1b. fm NCHW f32 -> NHWC bf16 ----------------
__global__ __launch_bounds__(256) void fmt_kernel(const float* __restrict__ in,
                                                  unsigned short* __restrict__ out) {
  __shared__ float tile[64][65];
  int p0 = blockIdx.x * 64, c0 = blockIdx.y * 64, b = blockIdx.z;
  int t = threadIdx.x, tx = t & 15, ty = t >> 4;
#pragma unroll
  for (int q = 0; q < 4; ++q) {
    int r = ty + q * 16;   // channel within tile
    float4 v = *(const float4*)&in[((long)b * CCH + c0 + r) * PDIM + p0 + tx * 4];
    tile[r][tx * 4 + 0] = v.x;
    tile[r][tx * 4 + 1] = v.y;
    tile[r][tx * 4 + 2] = v.z;
    tile[r][tx * 4 + 3] = v.w;
  }
  __syncthreads();
#pragma unroll
  for (int q = 0; q < 4; ++q) {
    int r = ty + q * 16;   // position within tile
    ushort4v o;
    o[0] = f2bf(tile[tx * 4 + 0][r]);
    o[1] = f2bf(tile[tx * 4 + 1][r]);
    o[2] = f2bf(tile[tx * 4 + 2][r]);
    o[3] = f2bf(tile[tx * 4 + 3][r]);
    *(ushort4v*)&out[((long)b * PDIM + p0 + r) * CCH + c0 + tx * 4] = o;
  }
}

// ---------------- 2. roi align (NHWC bf16 in) -> bf16 flat [928][12544] ----------------
__global__ __launch_bounds__(256) void roi_kernel(const unsigned short* __restrict__ fmT,
                                                  const float* __restrict__ rois,
                                                  unsigned short* __restrict__ A) {
  __shared__ int sidx[196][4];      // element offsets (pos*256) of the 4 taps
  __shared__ float swt[196][4];
  __shared__ unsigned short Arow[DDIM];   // 25088 B staging for coalesced writeout
  int roi = blockIdx.x;
  int t = threadIdx.x;
  float rx1 = rois[roi * 4 + 0], ry1 = rois[roi * 4 + 1];
  float rx2 = rois[roi * 4 + 2], ry2 = rois[roi * 4 + 3];
  float roiw = fmaxf(rx2 - rx1, 1.f), roih = fmaxf(ry2 - ry1, 1.f);
  float bw = roiw * (1.f / OUTP), bh = roih * (1.f / OUTP);
  if (t < 196) {
    int oy = t / 28, rem = t % 28, ox = rem / 4, s = rem % 4, sy = s >> 1, sx = s & 1;
    float y = ry1 + ((float)oy + ((float)sy + 0.5f) * 0.5f) * bh;
    float x = rx1 + ((float)ox + ((float)sx + 0.5f) * 0.5f) * bw;
    bool valid = (y >= -1.f) && (y <= 64.f) && (x >= -1.f) && (x <= 64.f);
    float yc = fminf(fmaxf(y, 0.f), 63.f);
    float xc = fminf(fmaxf(x, 0.f), 63.f);
    int y0 = (int)floorf(yc), x0 = (int)floorf(xc);
    int y1i = min(y0 + 1, 63), x1i = min(x0 + 1, 63);
    float ly = yc - (float)y0, lx = xc - (float)x0;
    float hy = 1.f - ly, hx = 1.f - lx;
    float m = valid ? 1.f : 0.f;
    swt[t][0] = hy * hx * m;
    swt[t][1] = hy * lx * m;
    swt[t][2] = ly * hx * m;
    swt[t][3] = ly * lx * m;
    sidx[t][0] = (y0 * 64 + x0) * CCH;
    sidx[t][1] = (y0 * 64 + x1i) * CCH;
    sidx[t][2] = (y1i * 64 + x0) * CCH;
    sidx[t][3] = (y1i * 64 + x1i) * CCH;
  }
  __syncthreads();
  int b = roi / RREG;
  const unsigned short* base = fmT + (long)b * PDIM * CCH + t;   // t = channel
  for (int bin = 0; bin < 49; ++bin) {
    float acc = 0.f;
#pragma unroll
    for (int s = 0; s < 4; ++s) {
      int sid = bin * 4 + s;
      acc += swt[sid][0] * bf2f(base[sidx[sid][0]])
           + swt[sid][1] * bf2f(base[sidx[sid][1]])
           + swt[sid][2] * bf2f(base[sidx[sid][2]])
           + swt[sid][3] * bf2f(base[sidx[sid][3]]);
    }
    Arow[t * 49 + bin] = f2bf(acc * 0.25f);
  }
  __syncthreads();
  const ushort8v* src = (const ushort8v*)Arow;
  ushort8v* dst = (ushort8v*)(A + (long)roi * DDIM);
  for (int i = t; i < DDIM / 8; i += 256) dst[i] = src[i];
}

// ---------------- 3. transpose f32 [K][N] -> bf16 [N][K] ----------------
__global__ __launch_bounds__(256) void transpose_kernel(const float* __restrict__ in,
                                                        unsigned short* __restrict__ out,
                                                        int K, int N) {
  __shared__ float tile[64][65];
  int k0 = blockIdx.x * 64, n0 = blockIdx.y * 64;
  int t = threadIdx.x, tx = t & 15, ty = t >> 4;
#pragma unroll
  for (int p = 0; p < 4; ++p) {
    int r = ty + p * 16;
    float4 v = *(const float4*)&in[(long)(k0 + r) * N + n0 + tx * 4];
    tile[r][tx * 4 + 0] = v.x;
    tile[r][tx * 4 + 1] = v.y;
    tile[r][tx * 4 + 2] = v.z;
    tile[r][tx * 4 + 3] = v.w;
  }
  __syncthreads();
#pragma unroll
  for (int p = 0; p < 4; ++p) {
    int r = ty + p * 16;
    ushort4v o;
    o[0] = f2bf(tile[tx * 4 + 0][r]);
    o[1] = f2bf(tile[tx * 4 + 1][r]);
    o[2] = f2bf(tile[tx * 4 + 2][r]);
    o[3] = f2bf(tile[tx * 4 + 3][r]);
    *(ushort4v*)&out[(long)(n0 + r) * K + k0 + tx * 4] = o;
  }
}

// ---------------- 4. bf16 MFMA GEMM: C[M][N] = A[M][K] * Bt[N][K]^T ----------------
__global__ __launch_bounds__(256) void gemm_kernel(const unsigned short* __restrict__ A,
                                                   const unsigned short* __restrict__ Bt,
                                                   float* __restrict__ C,
                                                   int M, int N, int K) {
  __shared__ unsigned short As[128][40];   // +8 pad -> 2-way bank aliasing (free)
  __shared__ unsigned short Bs[64][40];
  int t = threadIdx.x;
  int lane = t & 63, wv = t >> 6;
  int wr = wv >> 1, wc = wv & 1;           // wave grid 2x2 over 128x64
  int bm = blockIdx.x, bn = blockIdx.y;
  f32x4 acc[4][2];
#pragma unroll
  for (int m = 0; m < 4; ++m)
#pragma unroll
    for (int n = 0; n < 2; ++n) acc[m][n] = (f32x4){0.f, 0.f, 0.f, 0.f};

  int arow = t >> 1, ah = t & 1;           // A stage: 2 thr/row, 16 elems each
  long aoff = (long)(bm * 128 + arow) * K + ah * 16;
  bool av = (bm * 128 + arow) < M;
  int brow = t >> 2, bq = t & 3;           // B stage: 4 thr/row, 8 elems each
  long boff = (long)(bn * 64 + brow) * K + bq * 8;
  int fr = lane & 15, kk = (lane >> 4) * 8;

  for (int k0 = 0; k0 < K; k0 += 32) {
    __syncthreads();
    if (av) {
      *(ushort8v*)&As[arow][ah * 16]     = *(const ushort8v*)(A + aoff + k0);
      *(ushort8v*)&As[arow][ah * 16 + 8] = *(const ushort8v*)(A + aoff + k0 + 8);
    } else {
      ushort8v z = {0, 0, 0, 0, 0, 0, 0, 0};
      *(ushort8v*)&As[arow][ah * 16] = z;
      *(ushort8v*)&As[arow][ah * 16 + 8] = z;
    }
    *(ushort8v*)&Bs[brow][bq * 8] = *(const ushort8v*)(Bt + boff + k0);
    __syncthreads();
    bf16x8 af[4], bfr[2];
#pragma unroll
    for (int m = 0; m < 4; ++m) af[m] = *(bf16x8*)&As[wr * 64 + m * 16 + fr][kk];
#pragma unroll
    for (int n = 0; n < 2; ++n) bfr[n] = *(bf16x8*)&Bs[wc * 32 + n * 16 + fr][kk];
#pragma unroll
    for (int m = 0; m < 4; ++m)
#pragma unroll
      for (int n = 0; n < 2; ++n)
        acc[m][n] = __builtin_amdgcn_mfma_f32_16x16x32_bf16(af[m], bfr[n], acc[m][n], 0, 0, 0);
  }

  int fq = lane >> 4;
#pragma unroll
  for (int m = 0; m < 4; ++m)
#pragma unroll
    for (int n = 0; n < 2; ++n) {
      int col = bn * 64 + wc * 32 + n * 16 + fr;
#pragma unroll
      for (int j = 0; j < 4; ++j) {
        int row = bm * 128 + wr * 64 + m * 16 + fq * 4 + j;
        if (row < M) C[(long)row * N + col] = acc[m][n][j];
      }
    }
}

// ---------------- block reduce helper ----------------
static __device__ __forceinline__ void block_reduce2(float& a, float& b, float* sm) {
#pragma unroll
  for (int off = 32; off > 0; off >>= 1) {
    a += __shfl_down(a, off);
    b += __shfl_down(b, off);
  }
  int lane = threadIdx.x & 63, wv = threadIdx.x >> 6;
  if (lane == 0) { sm[wv] = a; sm[wv + 4] = b; }
  __syncthreads();
  a = sm[0] + sm[1] + sm[2] + sm[3];
  b = sm[4] + sm[5] + sm[6] + sm[7];
}

// ---------------- 5. bias + LN + ReLU -> bf16 h ----------------
__global__ __launch_bounds__(256) void ln1_kernel(const float* __restrict__ X,
                                                  const float* __restrict__ b1,
                                                  const float* __restrict__ g1,
                                                  const float* __restrict__ be1,
                                                  unsigned short* __restrict__ H) {
  __shared__ float sm[8];
  int row = blockIdx.x, t = threadIdx.x;
  float x[8];
  float sum = 0.f, sq = 0.f;
#pragma unroll
  for (int i = 0; i < 8; ++i) {
    int j = t + i * 256;
    x[i] = X[(long)row * N1DIM + j] + b1[j];
    sum += x[i];
    sq += x[i] * x[i];
  }
  block_reduce2(sum, sq, sm);
  float mu = sum * (1.f / N1DIM);
  float inv = rsqrtf(sq * (1.f / N1DIM) - mu * mu + 1e-5f);
#pragma unroll
  for (int i = 0; i < 8; ++i) {
    int j = t + i * 256;
    float y = fmaxf((x[i] - mu) * inv * g1[j] + be1[j], 0.f);
    H[(long)row * N1DIM + j] = f2bf(y);
  }
}

// ---------------- 6. bias + LN + missing-token select -> out ----------------
__global__ __launch_bounds__(256) void ln2_kernel(const float* __restrict__ X,
                                                  const float* __restrict__ b2,
                                                  const float* __restrict__ g2,
                                                  const float* __restrict__ be2,
                                                  const float* __restrict__ miss,
                                                  const int* __restrict__ det,
                                                  float* __restrict__ out) {
  __shared__ float sm[8];
  int row = blockIdx.x, t = threadIdx.x;
  float x[3];
  float sum = 0.f, sq = 0.f;
#pragma unroll
  for (int i = 0; i < 3; ++i) {
    int j = t + i * 256;
    x[i] = X[(long)row * FDIM + j] + b2[j];
    sum += x[i];
    sq += x[i] * x[i];
  }
  block_reduce2(sum, sq, sm);
  float mu = sum * (1.f / FDIM);
  float inv = rsqrtf(sq * (1.f / FDIM) - mu * mu + 1e-5f);
  int dv = det[row];
#pragma unroll
  for (int i = 0; i < 3; ++i) {
    int j = t + i * 256;
    float y = (x[i] - mu) * inv * g2[j] + be2[j];
    out[(long)row * FDIM + j] = dv ? y : miss[j];
  }
}

extern "C" void kernel_launch(void* const* d_in, const int* in_sizes, int n_in,
                              void* d_out, int out_size, void* d_ws, size_t ws_size,
                              hipStream_t stream) {
  const float* fm     = (const float*)d_in[0];
  const float* boxes  = (const float*)d_in[1];
  const float* scores = (const float*)d_in[2];
  const int*   labels = (const int*)d_in[3];
  const float* w1     = (const float*)d_in[4];
  const float* b1     = (const float*)d_in[5];
  const float* g1     = (const float*)d_in[6];
  const float* be1    = (const float*)d_in[7];
  const float* w2     = (const float*)d_in[8];
  const float* b2     = (const float*)d_in[9];
  const float* g2     = (const float*)d_in[10];
  const float* be2    = (const float*)d_in[11];
  const float* miss   = (const float*)d_in[12];
  float* out = (float*)d_out;
  char* ws = (char*)d_ws;

  float* rois = (float*)(ws + OFF_ROIS);
  int* det = (int*)(ws + OFF_DET);
  unsigned short* Abf = (unsigned short*)(ws + OFF_A);
  unsigned short* fmT = (unsigned short*)(ws + OFF_FMT);
  unsigned short* w1t = (unsigned short*)(ws + OFF_W1T);
  unsigned short* w2t = (unsigned short*)(ws + OFF_W2T);
  float* G1 = (float*)(ws + OFF_G1);
  unsigned short* Hbf = (unsigned short*)(ws + OFF_H);
  float* G2 = (float*)(ws + OFF_G2);

  hipLaunchKernelGGL(select_kernel, dim3(4), dim3(256), 0, stream,
                     boxes, scores, labels, rois, det, out + (long)MROWS * FDIM);
  hipLaunchKernelGGL(fmt_kernel, dim3(PDIM / 64, CCH / 64, BATCH), dim3(256), 0, stream,
                     fm, fmT);
  hipLaunchKernelGGL(roi_kernel, dim3(MROWS), dim3(256), 0, stream, fmT, rois, Abf);
  // fmT dead from here; w1t overwrites its region (stream-ordered)
  hipLaunchKernelGGL(transpose_kernel, dim3(DDIM / 64, N1DIM / 64), dim3(256), 0, stream,
                     w1, w1t, DDIM, N1DIM);
  hipLaunchKernelGGL(transpose_kernel, dim3(N1DIM / 64, FDIM / 64), dim3(256), 0, stream,
                     w2, w2t, N1DIM, FDIM);
  hipLaunchKernelGGL(gemm_kernel, dim3(8, N1DIM / 64), dim3(256), 0, stream,
                     Abf, w1t, G1, MROWS, N1DIM, DDIM);
  hipLaunchKernelGGL(ln1_kernel, dim3(MROWS), dim3(256), 0, stream, G1, b1, g1, be1, Hbf);
  hipLaunchKernelGGL(gemm_kernel, dim3(8, FDIM / 64), dim3(256), 0, stream,
                     Hbf, w2t, G2, MROWS, FDIM, N1DIM);
  hipLaunchKernelGGL(ln2_kernel, dim3(MROWS), dim3(256), 0, stream,
                     G2, b2, g2, be2, miss, det, out);
}

// Round 3
// 211.191 us; speedup vs baseline: 5.0660x; 2.2129x over previous
//
#include <hip/hip_runtime.h>

typedef __bf16 bf16x8 __attribute__((ext_vector_type(8)));
typedef float f32x4 __attribute__((ext_vector_type(4)));
typedef unsigned short ushort8v __attribute__((ext_vector_type(8)));
typedef unsigned short ushort4v __attribute__((ext_vector_type(4)));

#define BATCH 32
#define NBOX 40
#define CCH 256
#define HF 64
#define WF 64
#define RREG 29
#define OUTP 7
#define MROWS 928           // BATCH*RREG
#define DDIM 12544          // CCH*7*7
#define N1DIM 2048
#define FDIM 768
#define PDIM 4096           // HF*WF
#define S1 4                // split-K factor GEMM1
#define S2 8                // split-K factor GEMM2

// ---- workspace layout (bytes), lifetime-aliased ----
static constexpr size_t OFF_ROIS = 0;                                   // 928*4 f32
static constexpr size_t OFF_DET  = 16384;                               // 928 i32
static constexpr size_t OFF_A    = 32768;                               // bf16 [928][12544]
static constexpr size_t OFF_W1T  = OFF_A   + (size_t)MROWS * DDIM * 2;  // bf16 [2048][12544]
static constexpr size_t OFF_FMT  = OFF_W1T;                             // bf16 [32][4096][256] (dead after roi)
static constexpr size_t OFF_W2T  = OFF_W1T + (size_t)DDIM * N1DIM * 2;  // bf16 [768][2048]
static constexpr size_t OFF_GP   = OFF_W2T + (size_t)N1DIM * FDIM * 2;  // f32 [S1][928][2048]; later [S2][928][768]
static constexpr size_t OFF_H    = OFF_W1T;                             // bf16 [928][2048] (W1T dead after gemm1)

static __device__ __forceinline__ unsigned short f2bf(float f) {
  __bf16 h = (__bf16)f;
  return __builtin_bit_cast(unsigned short, h);
}
static __device__ __forceinline__ float bf2f(unsigned short u) {
  unsigned int x = ((unsigned int)u) << 16;
  return __builtin_bit_cast(float, x);
}
static __device__ __forceinline__ void gload_lds16(const void* g, void* l) {
  __builtin_amdgcn_global_load_lds((const __attribute__((address_space(1))) void*)g,
                                   (__attribute__((address_space(3))) void*)l, 16, 0, 0);
}

// ---------------- 1. box selection ----------------
__global__ __launch_bounds__(256) void select_kernel(const float* __restrict__ boxes,
                                                     const float* __restrict__ scores,
                                                     const int* __restrict__ labels,
                                                     float* __restrict__ rois,
                                                     int* __restrict__ det,
                                                     float* __restrict__ out_det) {
  int tid = blockIdx.x * 256 + threadIdx.x;
  if (tid >= MROWS) return;
  int b = tid / RREG, r = tid % RREG;
  float bestS = -1.0f;
  int bestN = 0;
  int found = 0;
  for (int n = 0; n < NBOX; ++n) {
    int lab = labels[b * NBOX + n];
    int ri = min(max(lab, 1), RREG) - 1;
    if (ri == r) {
      found = 1;
      float s = scores[b * NBOX + n];
      if (s > bestS) { bestS = s; bestN = n; }
    }
  }
  const float scale = 0.0625f;
  float4 bx = *(const float4*)&boxes[(b * NBOX + bestN) * 4];
  rois[tid * 4 + 0] = bx.x * scale;
  rois[tid * 4 + 1] = bx.y * scale;
  rois[tid * 4 + 2] = bx.z * scale;
  rois[tid * 4 + 3] = bx.w * scale;
  det[tid] = found;
  out_det[tid] = found ? 1.0f : 0.0f;
}

// ---------------- 1b. fm NCHW f32 -> NHWC bf16 ----------------
__global__ __launch_bounds__(256) void fmt_kernel(const float* __restrict__ in,
                                                  unsigned short* __restrict__ out) {
  __shared__ float tile[64][65];
  int p0 = blockIdx.x * 64, c0 = blockIdx.y * 64, b = blockIdx.z;
  int t = threadIdx.x, tx = t & 15, ty = t >> 4;
#pragma unroll
  for (int q = 0; q < 4; ++q) {
    int r = ty + q * 16;
    float4 v = *(const float4*)&in[((long)b * CCH + c0 + r) * PDIM + p0 + tx * 4];
    tile[r][tx * 4 + 0] = v.x;
    tile[r][tx * 4 + 1] = v.y;
    tile[r][tx * 4 + 2] = v.z;
    tile[r][tx * 4 + 3] = v.w;
  }
  __syncthreads();
#pragma unroll
  for (int q = 0; q < 4; ++q) {
    int r = ty + q * 16;
    ushort4v o;
    o[0] = f2bf(tile[tx * 4 + 0][r]);
    o[1] = f2bf(tile[tx * 4 + 1][r]);
    o[2] = f2bf(tile[tx * 4 + 2][r]);
    o[3] = f2bf(tile[tx * 4 + 3][r]);
    *(ushort4v*)&out[((long)b * PDIM + p0 + r) * CCH + c0 + tx * 4] = o;
  }
}

// ---------------- 2. roi align (NHWC bf16) -> bf16 [928][12544] ----------------
__global__ __launch_bounds__(256) void roi_kernel(const unsigned short* __restrict__ fmT,
                                                  const float* __restrict__ rois,
                                                  unsigned short* __restrict__ A) {
  __shared__ int sidx[196][4];
  __shared__ float swt[196][4];
  __shared__ unsigned short Arow[DDIM];
  int roi = blockIdx.x;
  int t = threadIdx.x;
  float rx1 = rois[roi * 4 + 0], ry1 = rois[roi * 4 + 1];
  float rx2 = rois[roi * 4 + 2], ry2 = rois[roi * 4 + 3];
  float roiw = fmaxf(rx2 - rx1, 1.f), roih = fmaxf(ry2 - ry1, 1.f);
  float bw = roiw * (1.f / OUTP), bh = roih * (1.f / OUTP);
  if (t < 196) {
    int oy = t / 28, rem = t % 28, ox = rem / 4, s = rem % 4, sy = s >> 1, sx = s & 1;
    float y = ry1 + ((float)oy + ((float)sy + 0.5f) * 0.5f) * bh;
    float x = rx1 + ((float)ox + ((float)sx + 0.5f) * 0.5f) * bw;
    bool valid = (y >= -1.f) && (y <= 64.f) && (x >= -1.f) && (x <= 64.f);
    float yc = fminf(fmaxf(y, 0.f), 63.f);
    float xc = fminf(fmaxf(x, 0.f), 63.f);
    int y0 = (int)floorf(yc), x0 = (int)floorf(xc);
    int y1i = min(y0 + 1, 63), x1i = min(x0 + 1, 63);
    float ly = yc - (float)y0, lx = xc - (float)x0;
    float hy = 1.f - ly, hx = 1.f - lx;
    float m = valid ? 1.f : 0.f;
    swt[t][0] = hy * hx * m;
    swt[t][1] = hy * lx * m;
    swt[t][2] = ly * hx * m;
    swt[t][3] = ly * lx * m;
    sidx[t][0] = (y0 * 64 + x0) * CCH;
    sidx[t][1] = (y0 * 64 + x1i) * CCH;
    sidx[t][2] = (y1i * 64 + x0) * CCH;
    sidx[t][3] = (y1i * 64 + x1i) * CCH;
  }
  __syncthreads();
  int b = roi / RREG;
  const unsigned short* base = fmT + (long)b * PDIM * CCH + t;   // t = channel
  for (int bin = 0; bin < 49; ++bin) {
    float acc = 0.f;
#pragma unroll
    for (int s = 0; s < 4; ++s) {
      int sid = bin * 4 + s;
      acc += swt[sid][0] * bf2f(base[sidx[sid][0]])
           + swt[sid][1] * bf2f(base[sidx[sid][1]])
           + swt[sid][2] * bf2f(base[sidx[sid][2]])
           + swt[sid][3] * bf2f(base[sidx[sid][3]]);
    }
    Arow[t * 49 + bin] = f2bf(acc * 0.25f);
  }
  __syncthreads();
  const ushort8v* src = (const ushort8v*)Arow;
  ushort8v* dst = (ushort8v*)(A + (long)roi * DDIM);
  for (int i = t; i < DDIM / 8; i += 256) dst[i] = src[i];
}

// ---------------- 3. transpose f32 [K][N] -> bf16 [N][K] ----------------
__global__ __launch_bounds__(256) void transpose_kernel(const float* __restrict__ in,
                                                        unsigned short* __restrict__ out,
                                                        int K, int N) {
  __shared__ float tile[64][65];
  int k0 = blockIdx.x * 64, n0 = blockIdx.y * 64;
  int t = threadIdx.x, tx = t & 15, ty = t >> 4;
#pragma unroll
  for (int p = 0; p < 4; ++p) {
    int r = ty + p * 16;
    float4 v = *(const float4*)&in[(long)(k0 + r) * N + n0 + tx * 4];
    tile[r][tx * 4 + 0] = v.x;
    tile[r][tx * 4 + 1] = v.y;
    tile[r][tx * 4 + 2] = v.z;
    tile[r][tx * 4 + 3] = v.w;
  }
  __syncthreads();
#pragma unroll
  for (int p = 0; p < 4; ++p) {
    int r = ty + p * 16;
    ushort4v o;
    o[0] = f2bf(tile[tx * 4 + 0][r]);
    o[1] = f2bf(tile[tx * 4 + 1][r]);
    o[2] = f2bf(tile[tx * 4 + 2][r]);
    o[3] = f2bf(tile[tx * 4 + 3][r]);
    *(ushort4v*)&out[(long)(n0 + r) * K + k0 + tx * 4] = o;
  }
}

// ---------------- 4. split-K bf16 MFMA GEMM (m97 structure) ----------------
// C_partial[s][M][N] = A[M][K(sub)] * Bt[N][K(sub)]^T, 128x128 tile, BK=64,
// global_load_lds width-16 staging, XOR-swizzled LDS (chunk ^= row&7).
__global__ __launch_bounds__(256, 2) void gemm_sk_kernel(const unsigned short* __restrict__ A,
                                                         const unsigned short* __restrict__ Bt,
                                                         float* __restrict__ Cp,
                                                         int M, int N, int K, int kchunk) {
  __shared__ unsigned short As[128 * 64];   // linear [row][chunk^(row&7)] bf16
  __shared__ unsigned short Bs[128 * 64];
  int t = threadIdx.x;
  int lane = t & 63, wv = t >> 6;
  int wr = wv >> 1, wc = wv & 1;            // wave quadrant of 128x128
  int bm = blockIdx.x, bn = blockIdx.y, s = blockIdx.z;
  int fr = lane & 15, fq = lane >> 4;

  f32x4 acc[4][4];
#pragma unroll
  for (int m = 0; m < 4; ++m)
#pragma unroll
    for (int n = 0; n < 4; ++n) acc[m][n] = (f32x4){0.f, 0.f, 0.f, 0.f};

  int srow = t >> 3;                        // staging row base (0..31), +i*32
  int scol = t & 7;                         // 16B chunk index within 128B row
  int k_begin = s * kchunk;
  int k_end = k_begin + kchunk;

  // precompute global row indices (A rows clamped to M-1; dup rows unread)
  int garow[4], gbrow[4], schunk[4];
#pragma unroll
  for (int i = 0; i < 4; ++i) {
    int row = srow + i * 32;
    schunk[i] = (scol ^ (row & 7)) * 8;     // element offset of swizzled source chunk
    garow[i] = min(bm * 128 + row, M - 1);
    gbrow[i] = bn * 128 + row;
  }

  for (int k0 = k_begin; k0 < k_end; k0 += 64) {
    __syncthreads();
#pragma unroll
    for (int i = 0; i < 4; ++i)
      gload_lds16(A + (long)garow[i] * K + k0 + schunk[i],
                  (char*)As + t * 16 + i * 4096);
#pragma unroll
    for (int i = 0; i < 4; ++i)
      gload_lds16(Bt + (long)gbrow[i] * K + k0 + schunk[i],
                  (char*)Bs + t * 16 + i * 4096);
    __syncthreads();   // compiler emits vmcnt(0) drain before s_barrier

#pragma unroll
    for (int ks = 0; ks < 2; ++ks) {
      bf16x8 af[4], bfv[4];
#pragma unroll
      for (int m = 0; m < 4; ++m) {
        int row = wr * 64 + m * 16 + fr;
        int bc = (ks * 64 + fq * 16) ^ ((row & 7) << 4);
        af[m] = *(const bf16x8*)((const char*)As + row * 128 + bc);
      }
#pragma unroll
      for (int n = 0; n < 4; ++n) {
        int row = wc * 64 + n * 16 + fr;
        int bc = (ks * 64 + fq * 16) ^ ((row & 7) << 4);
        bfv[n] = *(const bf16x8*)((const char*)Bs + row * 128 + bc);
      }
#pragma unroll
      for (int m = 0; m < 4; ++m)
#pragma unroll
        for (int n = 0; n < 4; ++n)
          acc[m][n] = __builtin_amdgcn_mfma_f32_16x16x32_bf16(af[m], bfv[n], acc[m][n], 0, 0, 0);
    }
  }

  float* Cb = Cp + (long)s * M * N;
#pragma unroll
  for (int m = 0; m < 4; ++m)
#pragma unroll
    for (int n = 0; n < 4; ++n) {
      int col = bn * 128 + wc * 64 + n * 16 + fr;
#pragma unroll
      for (int j = 0; j < 4; ++j) {
        int row = bm * 128 + wr * 64 + m * 16 + fq * 4 + j;
        if (row < M) Cb[(long)row * N + col] = acc[m][n][j];
      }
    }
}

// ---------------- block reduce helper ----------------
static __device__ __forceinline__ void block_reduce2(float& a, float& b, float* sm) {
#pragma unroll
  for (int off = 32; off > 0; off >>= 1) {
    a += __shfl_down(a, off);
    b += __shfl_down(b, off);
  }
  int lane = threadIdx.x & 63, wv = threadIdx.x >> 6;
  if (lane == 0) { sm[wv] = a; sm[wv + 4] = b; }
  __syncthreads();
  a = sm[0] + sm[1] + sm[2] + sm[3];
  b = sm[4] + sm[5] + sm[6] + sm[7];
}

// ---------------- 5. partial-sum + bias + LN + ReLU -> bf16 h ----------------
__global__ __launch_bounds__(256) void ln1_kernel(const float* __restrict__ X,
                                                  const float* __restrict__ b1,
                                                  const float* __restrict__ g1,
                                                  const float* __restrict__ be1,
                                                  unsigned short* __restrict__ H) {
  __shared__ float sm[8];
  int row = blockIdx.x, t = threadIdx.x;
  float x[8];
  float sum = 0.f, sq = 0.f;
#pragma unroll
  for (int i = 0; i < 8; ++i) {
    int j = t + i * 256;
    float v = b1[j];
#pragma unroll
    for (int s = 0; s < S1; ++s) v += X[((long)s * MROWS + row) * N1DIM + j];
    x[i] = v;
    sum += v;
    sq += v * v;
  }
  block_reduce2(sum, sq, sm);
  float mu = sum * (1.f / N1DIM);
  float inv = rsqrtf(sq * (1.f / N1DIM) - mu * mu + 1e-5f);
#pragma unroll
  for (int i = 0; i < 8; ++i) {
    int j = t + i * 256;
    float y = fmaxf((x[i] - mu) * inv * g1[j] + be1[j], 0.f);
    H[(long)row * N1DIM + j] = f2bf(y);
  }
}

// ---------------- 6. partial-sum + bias + LN + missing-token -> out ----------------
__global__ __launch_bounds__(256) void ln2_kernel(const float* __restrict__ X,
                                                  const float* __restrict__ b2,
                                                  const float* __restrict__ g2,
                                                  const float* __restrict__ be2,
                                                  const float* __restrict__ miss,
                                                  const int* __restrict__ det,
                                                  float* __restrict__ out) {
  __shared__ float sm[8];
  int row = blockIdx.x, t = threadIdx.x;
  float x[3];
  float sum = 0.f, sq = 0.f;
#pragma unroll
  for (int i = 0; i < 3; ++i) {
    int j = t + i * 256;
    float v = b2[j];
#pragma unroll
    for (int s = 0; s < S2; ++s) v += X[((long)s * MROWS + row) * FDIM + j];
    x[i] = v;
    sum += v;
    sq += v * v;
  }
  block_reduce2(sum, sq, sm);
  float mu = sum * (1.f / FDIM);
  float inv = rsqrtf(sq * (1.f / FDIM) - mu * mu + 1e-5f);
  int dv = det[row];
#pragma unroll
  for (int i = 0; i < 3; ++i) {
    int j = t + i * 256;
    float y = (x[i] - mu) * inv * g2[j] + be2[j];
    out[(long)row * FDIM + j] = dv ? y : miss[j];
  }
}

extern "C" void kernel_launch(void* const* d_in, const int* in_sizes, int n_in,
                              void* d_out, int out_size, void* d_ws, size_t ws_size,
                              hipStream_t stream) {
  const float* fm     = (const float*)d_in[0];
  const float* boxes  = (const float*)d_in[1];
  const float* scores = (const float*)d_in[2];
  const int*   labels = (const int*)d_in[3];
  const float* w1     = (const float*)d_in[4];
  const float* b1     = (const float*)d_in[5];
  const float* g1     = (const float*)d_in[6];
  const float* be1    = (const float*)d_in[7];
  const float* w2     = (const float*)d_in[8];
  const float* b2     = (const float*)d_in[9];
  const float* g2     = (const float*)d_in[10];
  const float* be2    = (const float*)d_in[11];
  const float* miss   = (const float*)d_in[12];
  float* out = (float*)d_out;
  char* ws = (char*)d_ws;

  float* rois = (float*)(ws + OFF_ROIS);
  int* det = (int*)(ws + OFF_DET);
  unsigned short* Abf = (unsigned short*)(ws + OFF_A);
  unsigned short* fmT = (unsigned short*)(ws + OFF_FMT);
  unsigned short* w1t = (unsigned short*)(ws + OFF_W1T);
  unsigned short* w2t = (unsigned short*)(ws + OFF_W2T);
  float* Gp = (float*)(ws + OFF_GP);
  unsigned short* Hbf = (unsigned short*)(ws + OFF_H);

  hipLaunchKernelGGL(select_kernel, dim3(4), dim3(256), 0, stream,
                     boxes, scores, labels, rois, det, out + (long)MROWS * FDIM);
  hipLaunchKernelGGL(fmt_kernel, dim3(PDIM / 64, CCH / 64, BATCH), dim3(256), 0, stream,
                     fm, fmT);
  hipLaunchKernelGGL(roi_kernel, dim3(MROWS), dim3(256), 0, stream, fmT, rois, Abf);
  // fmT dead; w1t/w2t overwrite its region (stream-ordered)
  hipLaunchKernelGGL(transpose_kernel, dim3(DDIM / 64, N1DIM / 64), dim3(256), 0, stream,
                     w1, w1t, DDIM, N1DIM);
  hipLaunchKernelGGL(transpose_kernel, dim3(N1DIM / 64, FDIM / 64), dim3(256), 0, stream,
                     w2, w2t, N1DIM, FDIM);
  hipLaunchKernelGGL(gemm_sk_kernel, dim3(8, N1DIM / 128, S1), dim3(256), 0, stream,
                     Abf, w1t, Gp, MROWS, N1DIM, DDIM, DDIM / S1);
  hipLaunchKernelGGL(ln1_kernel, dim3(MROWS), dim3(256), 0, stream, Gp, b1, g1, be1, Hbf);
  // W1T dead (H aliases it); G1 partials consumed -> Gp reused for GEMM2 partials
  hipLaunchKernelGGL(gemm_sk_kernel, dim3(8, FDIM / 128, S2), dim3(256), 0, stream,
                     Hbf, w2t, Gp, MROWS, FDIM, N1DIM, N1DIM / S2);
  hipLaunchKernelGGL(ln2_kernel, dim3(MROWS), dim3(256), 0, stream,
                     Gp, b2, g2, be2, miss, det, out);
}

// Round 5
// 190.958 us; speedup vs baseline: 5.6028x; 1.1060x over previous
//
#include <hip/hip_runtime.h>

typedef __bf16 bf16x8 __attribute__((ext_vector_type(8)));
typedef float f32x4 __attribute__((ext_vector_type(4)));
typedef unsigned short ushort8v __attribute__((ext_vector_type(8)));
typedef unsigned short ushort4v __attribute__((ext_vector_type(4)));

#define BATCH 32
#define NBOX 40
#define CCH 256
#define HF 64
#define WF 64
#define RREG 29
#define OUTP 7
#define MROWS 928           // BATCH*RREG
#define DDIM 12544          // CCH*7*7
#define N1DIM 2048
#define FDIM 768
#define PDIM 4096           // HF*WF
#define S1 8                // split-K factor GEMM1
#define S2 8                // split-K factor GEMM2

// ---- workspace layout (bytes), lifetime-aliased ----
static constexpr size_t OFF_ROIS = 0;                                   // 928*4 f32
static constexpr size_t OFF_DET  = 16384;                               // 928 i32
static constexpr size_t OFF_A    = 32768;                               // bf16 [928][12544]
static constexpr size_t OFF_W1T  = OFF_A   + (size_t)MROWS * DDIM * 2;  // bf16 [2048][12544]
static constexpr size_t OFF_FMT  = OFF_W1T;                             // bf16 [32][4096][256] (dead after roi)
static constexpr size_t OFF_W2T  = OFF_W1T + (size_t)DDIM * N1DIM * 2;  // bf16 [768][2048]
static constexpr size_t OFF_GP   = OFF_W2T + (size_t)N1DIM * FDIM * 2;  // f32 [S1][928][2048]; later [S2][928][768]
static constexpr size_t OFF_H    = OFF_W1T;                             // bf16 [928][2048] (W1T dead after gemm1)

static __device__ __forceinline__ unsigned short f2bf(float f) {
  __bf16 h = (__bf16)f;
  return __builtin_bit_cast(unsigned short, h);
}
static __device__ __forceinline__ float bf2f(unsigned short u) {
  unsigned int x = ((unsigned int)u) << 16;
  return __builtin_bit_cast(float, x);
}
static __device__ __forceinline__ void gload_lds16(const void* g, void* l) {
  __builtin_amdgcn_global_load_lds((const __attribute__((address_space(1))) void*)g,
                                   (__attribute__((address_space(3))) void*)l, 16, 0, 0);
}

// ---------------- 1. box selection ----------------
__global__ __launch_bounds__(256) void select_kernel(const float* __restrict__ boxes,
                                                     const float* __restrict__ scores,
                                                     const int* __restrict__ labels,
                                                     float* __restrict__ rois,
                                                     int* __restrict__ det,
                                                     float* __restrict__ out_det) {
  int tid = blockIdx.x * 256 + threadIdx.x;
  if (tid >= MROWS) return;
  int b = tid / RREG, r = tid % RREG;
  float bestS = -1.0f;
  int bestN = 0;
  int found = 0;
  for (int n = 0; n < NBOX; ++n) {
    int lab = labels[b * NBOX + n];
    int ri = min(max(lab, 1), RREG) - 1;
    if (ri == r) {
      found = 1;
      float s = scores[b * NBOX + n];
      if (s > bestS) { bestS = s; bestN = n; }
    }
  }
  const float scale = 0.0625f;
  float4 bx = *(const float4*)&boxes[(b * NBOX + bestN) * 4];
  rois[tid * 4 + 0] = bx.x * scale;
  rois[tid * 4 + 1] = bx.y * scale;
  rois[tid * 4 + 2] = bx.z * scale;
  rois[tid * 4 + 3] = bx.w * scale;
  det[tid] = found;
  out_det[tid] = found ? 1.0f : 0.0f;
}

// ---------------- 1b. fm NCHW f32 -> NHWC bf16 ----------------
__global__ __launch_bounds__(256) void fmt_kernel(const float* __restrict__ in,
                                                  unsigned short* __restrict__ out) {
  __shared__ float tile[64][65];
  int p0 = blockIdx.x * 64, c0 = blockIdx.y * 64, b = blockIdx.z;
  int t = threadIdx.x, tx = t & 15, ty = t >> 4;
#pragma unroll
  for (int q = 0; q < 4; ++q) {
    int r = ty + q * 16;
    float4 v = *(const float4*)&in[((long)b * CCH + c0 + r) * PDIM + p0 + tx * 4];
    tile[r][tx * 4 + 0] = v.x;
    tile[r][tx * 4 + 1] = v.y;
    tile[r][tx * 4 + 2] = v.z;
    tile[r][tx * 4 + 3] = v.w;
  }
  __syncthreads();
#pragma unroll
  for (int q = 0; q < 4; ++q) {
    int r = ty + q * 16;
    ushort4v o;
    o[0] = f2bf(tile[tx * 4 + 0][r]);
    o[1] = f2bf(tile[tx * 4 + 1][r]);
    o[2] = f2bf(tile[tx * 4 + 2][r]);
    o[3] = f2bf(tile[tx * 4 + 3][r]);
    *(ushort4v*)&out[((long)b * PDIM + p0 + r) * CCH + c0 + tx * 4] = o;
  }
}

// ---------------- 2. roi align (NHWC bf16) -> bf16 [928][12544] ----------------
// thread t: channel group cg = t&63 (4 ch via ushort4 loads), bin subset sub = t>>6.
__global__ __launch_bounds__(256) void roi_kernel(const unsigned short* __restrict__ fmT,
                                                  const float* __restrict__ rois,
                                                  unsigned short* __restrict__ A) {
  __shared__ int sidx[196][4];
  __shared__ float swt[196][4];
  __shared__ unsigned short Arow[DDIM];
  int roi = blockIdx.x;
  int t = threadIdx.x;
  float rx1 = rois[roi * 4 + 0], ry1 = rois[roi * 4 + 1];
  float rx2 = rois[roi * 4 + 2], ry2 = rois[roi * 4 + 3];
  float roiw = fmaxf(rx2 - rx1, 1.f), roih = fmaxf(ry2 - ry1, 1.f);
  float bw = roiw * (1.f / OUTP), bh = roih * (1.f / OUTP);
  if (t < 196) {
    int oy = t / 28, rem = t % 28, ox = rem / 4, s = rem % 4, sy = s >> 1, sx = s & 1;
    float y = ry1 + ((float)oy + ((float)sy + 0.5f) * 0.5f) * bh;
    float x = rx1 + ((float)ox + ((float)sx + 0.5f) * 0.5f) * bw;
    bool valid = (y >= -1.f) && (y <= 64.f) && (x >= -1.f) && (x <= 64.f);
    float yc = fminf(fmaxf(y, 0.f), 63.f);
    float xc = fminf(fmaxf(x, 0.f), 63.f);
    int y0 = (int)floorf(yc), x0 = (int)floorf(xc);
    int y1i = min(y0 + 1, 63), x1i = min(x0 + 1, 63);
    float ly = yc - (float)y0, lx = xc - (float)x0;
    float hy = 1.f - ly, hx = 1.f - lx;
    float m = valid ? 1.f : 0.f;
    swt[t][0] = hy * hx * m;
    swt[t][1] = hy * lx * m;
    swt[t][2] = ly * hx * m;
    swt[t][3] = ly * lx * m;
    sidx[t][0] = (y0 * 64 + x0) * CCH;
    sidx[t][1] = (y0 * 64 + x1i) * CCH;
    sidx[t][2] = (y1i * 64 + x0) * CCH;
    sidx[t][3] = (y1i * 64 + x1i) * CCH;
  }
  __syncthreads();
  int b = roi / RREG;
  int cg = t & 63;                       // 4 channels: cg*4 .. cg*4+3
  int sub = t >> 6;                      // bin subset
  int start = sub * 12 + min(sub, 1);    // 0,13,25,37
  int cnt = sub == 0 ? 13 : 12;
  const unsigned short* base = fmT + (long)b * PDIM * CCH + cg * 4;
  for (int bi = 0; bi < cnt; ++bi) {
    int bin = start + bi;
    float a0 = 0.f, a1 = 0.f, a2 = 0.f, a3 = 0.f;
#pragma unroll
    for (int s = 0; s < 4; ++s) {
      int sid = bin * 4 + s;
#pragma unroll
      for (int tp = 0; tp < 4; ++tp) {
        float w = swt[sid][tp];
        ushort4v v = *(const ushort4v*)(base + sidx[sid][tp]);
        a0 += w * bf2f(v[0]);
        a1 += w * bf2f(v[1]);
        a2 += w * bf2f(v[2]);
        a3 += w * bf2f(v[3]);
      }
    }
    Arow[(cg * 4 + 0) * 49 + bin] = f2bf(a0 * 0.25f);
    Arow[(cg * 4 + 1) * 49 + bin] = f2bf(a1 * 0.25f);
    Arow[(cg * 4 + 2) * 49 + bin] = f2bf(a2 * 0.25f);
    Arow[(cg * 4 + 3) * 49 + bin] = f2bf(a3 * 0.25f);
  }
  __syncthreads();
  const ushort8v* src = (const ushort8v*)Arow;
  ushort8v* dst = (ushort8v*)(A + (long)roi * DDIM);
  for (int i = t; i < DDIM / 8; i += 256) dst[i] = src[i];
}

// ---------------- 3. transpose f32 [K][N] -> bf16 [N][K] ----------------
__global__ __launch_bounds__(256) void transpose_kernel(const float* __restrict__ in,
                                                        unsigned short* __restrict__ out,
                                                        int K, int N) {
  __shared__ float tile[64][65];
  int k0 = blockIdx.x * 64, n0 = blockIdx.y * 64;
  int t = threadIdx.x, tx = t & 15, ty = t >> 4;
#pragma unroll
  for (int p = 0; p < 4; ++p) {
    int r = ty + p * 16;
    float4 v = *(const float4*)&in[(long)(k0 + r) * N + n0 + tx * 4];
    tile[r][tx * 4 + 0] = v.x;
    tile[r][tx * 4 + 1] = v.y;
    tile[r][tx * 4 + 2] = v.z;
    tile[r][tx * 4 + 3] = v.w;
  }
  __syncthreads();
#pragma unroll
  for (int p = 0; p < 4; ++p) {
    int r = ty + p * 16;
    ushort4v o;
    o[0] = f2bf(tile[tx * 4 + 0][r]);
    o[1] = f2bf(tile[tx * 4 + 1][r]);
    o[2] = f2bf(tile[tx * 4 + 2][r]);
    o[3] = f2bf(tile[tx * 4 + 3][r]);
    *(ushort4v*)&out[(long)(n0 + r) * K + k0 + tx * 4] = o;
  }
}

// ---------------- 4. split-K bf16 MFMA GEMM (m97 structure + XCD swizzle) ----------------
// kchunk is a multiple of 64 (BK); device clamps k_end to K so the last split
// takes the remainder. Requires every split s to have k_begin < K.
__global__ __launch_bounds__(256, 3) void gemm_sk_kernel(const unsigned short* __restrict__ A,
                                                         const unsigned short* __restrict__ Bt,
                                                         float* __restrict__ Cp,
                                                         int M, int N, int K, int kchunk,
                                                         int gy, int q) {
  __shared__ unsigned short As[128 * 64];   // linear [row][chunk^(row&7)] bf16
  __shared__ unsigned short Bs[128 * 64];
  int bid = blockIdx.x;
  int tile = (bid & 7) * q + (bid >> 3);    // bijective XCD-chunked swizzle (nwg % 8 == 0)
  int bm = tile & 7;
  int rest = tile >> 3;
  int bn = rest % gy;
  int s = rest / gy;

  int t = threadIdx.x;
  int lane = t & 63, wv = t >> 6;
  int wr = wv >> 1, wc = wv & 1;
  int fr = lane & 15, fq = lane >> 4;

  f32x4 acc[4][4];
#pragma unroll
  for (int m = 0; m < 4; ++m)
#pragma unroll
    for (int n = 0; n < 4; ++n) acc[m][n] = (f32x4){0.f, 0.f, 0.f, 0.f};

  int srow = t >> 3;
  int scol = t & 7;
  int k_begin = s * kchunk;
  int k_end = min(k_begin + kchunk, K);     // BK-aligned split boundaries (R4 bug fix)

  int garow[4], gbrow[4], schunk[4];
#pragma unroll
  for (int i = 0; i < 4; ++i) {
    int row = srow + i * 32;
    schunk[i] = (scol ^ (row & 7)) * 8;
    garow[i] = min(bm * 128 + row, M - 1);
    gbrow[i] = bn * 128 + row;
  }

  for (int k0 = k_begin; k0 < k_end; k0 += 64) {
    __syncthreads();
#pragma unroll
    for (int i = 0; i < 4; ++i)
      gload_lds16(A + (long)garow[i] * K + k0 + schunk[i],
                  (char*)As + t * 16 + i * 4096);
#pragma unroll
    for (int i = 0; i < 4; ++i)
      gload_lds16(Bt + (long)gbrow[i] * K + k0 + schunk[i],
                  (char*)Bs + t * 16 + i * 4096);
    __syncthreads();

#pragma unroll
    for (int ks = 0; ks < 2; ++ks) {
      bf16x8 af[4], bfv[4];
#pragma unroll
      for (int m = 0; m < 4; ++m) {
        int row = wr * 64 + m * 16 + fr;
        int bc = (ks * 64 + fq * 16) ^ ((row & 7) << 4);
        af[m] = *(const bf16x8*)((const char*)As + row * 128 + bc);
      }
#pragma unroll
      for (int n = 0; n < 4; ++n) {
        int row = wc * 64 + n * 16 + fr;
        int bc = (ks * 64 + fq * 16) ^ ((row & 7) << 4);
        bfv[n] = *(const bf16x8*)((const char*)Bs + row * 128 + bc);
      }
#pragma unroll
      for (int m = 0; m < 4; ++m)
#pragma unroll
        for (int n = 0; n < 4; ++n)
          acc[m][n] = __builtin_amdgcn_mfma_f32_16x16x32_bf16(af[m], bfv[n], acc[m][n], 0, 0, 0);
    }
  }

  float* Cb = Cp + (long)s * M * N;
#pragma unroll
  for (int m = 0; m < 4; ++m)
#pragma unroll
    for (int n = 0; n < 4; ++n) {
      int col = bn * 128 + wc * 64 + n * 16 + fr;
#pragma unroll
      for (int j = 0; j < 4; ++j) {
        int row = bm * 128 + wr * 64 + m * 16 + fq * 4 + j;
        if (row < M) Cb[(long)row * N + col] = acc[m][n][j];
      }
    }
}

// ---------------- block reduce helper ----------------
static __device__ __forceinline__ void block_reduce2(float& a, float& b, float* sm) {
#pragma unroll
  for (int off = 32; off > 0; off >>= 1) {
    a += __shfl_down(a, off);
    b += __shfl_down(b, off);
  }
  int lane = threadIdx.x & 63, wv = threadIdx.x >> 6;
  if (lane == 0) { sm[wv] = a; sm[wv + 4] = b; }
  __syncthreads();
  a = sm[0] + sm[1] + sm[2] + sm[3];
  b = sm[4] + sm[5] + sm[6] + sm[7];
}

// ---------------- 5. partial-sum + bias + LN + ReLU -> bf16 h ----------------
__global__ __launch_bounds__(256) void ln1_kernel(const float* __restrict__ X,
                                                  const float* __restrict__ b1,
                                                  const float* __restrict__ g1,
                                                  const float* __restrict__ be1,
                                                  unsigned short* __restrict__ H) {
  __shared__ float sm[8];
  int row = blockIdx.x, t = threadIdx.x;
  float x[8];
  float sum = 0.f, sq = 0.f;
#pragma unroll
  for (int i = 0; i < 8; ++i) {
    int j = t + i * 256;
    float v = b1[j];
#pragma unroll
    for (int s = 0; s < S1; ++s) v += X[((long)s * MROWS + row) * N1DIM + j];
    x[i] = v;
    sum += v;
    sq += v * v;
  }
  block_reduce2(sum, sq, sm);
  float mu = sum * (1.f / N1DIM);
  float inv = rsqrtf(sq * (1.f / N1DIM) - mu * mu + 1e-5f);
#pragma unroll
  for (int i = 0; i < 8; ++i) {
    int j = t + i * 256;
    float y = fmaxf((x[i] - mu) * inv * g1[j] + be1[j], 0.f);
    H[(long)row * N1DIM + j] = f2bf(y);
  }
}

// ---------------- 6. partial-sum + bias + LN + missing-token -> out ----------------
__global__ __launch_bounds__(256) void ln2_kernel(const float* __restrict__ X,
                                                  const float* __restrict__ b2,
                                                  const float* __restrict__ g2,
                                                  const float* __restrict__ be2,
                                                  const float* __restrict__ miss,
                                                  const int* __restrict__ det,
                                                  float* __restrict__ out) {
  __shared__ float sm[8];
  int row = blockIdx.x, t = threadIdx.x;
  float x[3];
  float sum = 0.f, sq = 0.f;
#pragma unroll
  for (int i = 0; i < 3; ++i) {
    int j = t + i * 256;
    float v = b2[j];
#pragma unroll
    for (int s = 0; s < S2; ++s) v += X[((long)s * MROWS + row) * FDIM + j];
    x[i] = v;
    sum += v;
    sq += v * v;
  }
  block_reduce2(sum, sq, sm);
  float mu = sum * (1.f / FDIM);
  float inv = rsqrtf(sq * (1.f / FDIM) - mu * mu + 1e-5f);
  int dv = det[row];
#pragma unroll
  for (int i = 0; i < 3; ++i) {
    int j = t + i * 256;
    float y = (x[i] - mu) * inv * g2[j] + be2[j];
    out[(long)row * FDIM + j] = dv ? y : miss[j];
  }
}

extern "C" void kernel_launch(void* const* d_in, const int* in_sizes, int n_in,
                              void* d_out, int out_size, void* d_ws, size_t ws_size,
                              hipStream_t stream) {
  const float* fm     = (const float*)d_in[0];
  const float* boxes  = (const float*)d_in[1];
  const float* scores = (const float*)d_in[2];
  const int*   labels = (const int*)d_in[3];
  const float* w1     = (const float*)d_in[4];
  const float* b1     = (const float*)d_in[5];
  const float* g1     = (const float*)d_in[6];
  const float* be1    = (const float*)d_in[7];
  const float* w2     = (const float*)d_in[8];
  const float* b2     = (const float*)d_in[9];
  const float* g2     = (const float*)d_in[10];
  const float* be2    = (const float*)d_in[11];
  const float* miss   = (const float*)d_in[12];
  float* out = (float*)d_out;
  char* ws = (char*)d_ws;

  float* rois = (float*)(ws + OFF_ROIS);
  int* det = (int*)(ws + OFF_DET);
  unsigned short* Abf = (unsigned short*)(ws + OFF_A);
  unsigned short* fmT = (unsigned short*)(ws + OFF_FMT);
  unsigned short* w1t = (unsigned short*)(ws + OFF_W1T);
  unsigned short* w2t = (unsigned short*)(ws + OFF_W2T);
  float* Gp = (float*)(ws + OFF_GP);
  unsigned short* Hbf = (unsigned short*)(ws + OFF_H);

  hipLaunchKernelGGL(select_kernel, dim3(4), dim3(256), 0, stream,
                     boxes, scores, labels, rois, det, out + (long)MROWS * FDIM);
  hipLaunchKernelGGL(fmt_kernel, dim3(PDIM / 64, CCH / 64, BATCH), dim3(256), 0, stream,
                     fm, fmT);
  hipLaunchKernelGGL(roi_kernel, dim3(MROWS), dim3(256), 0, stream, fmT, rois, Abf);
  // fmT dead; w1t/w2t overwrite its region (stream-ordered)
  hipLaunchKernelGGL(transpose_kernel, dim3(DDIM / 64, N1DIM / 64), dim3(256), 0, stream,
                     w1, w1t, DDIM, N1DIM);
  hipLaunchKernelGGL(transpose_kernel, dim3(N1DIM / 64, FDIM / 64), dim3(256), 0, stream,
                     w2, w2t, N1DIM, FDIM);
  {
    // GEMM1: K = 196 k-blocks; kchunk = ceil(196/S1)*64 = 1600 (s=7 takes 1344)
    int nkb = DDIM / 64;
    int kc = ((nkb + S1 - 1) / S1) * 64;
    int gy = N1DIM / 128, nwg = 8 * gy * S1;          // 1024
    hipLaunchKernelGGL(gemm_sk_kernel, dim3(nwg), dim3(256), 0, stream,
                       Abf, w1t, Gp, MROWS, N1DIM, DDIM, kc, gy, nwg / 8);
  }
  hipLaunchKernelGGL(ln1_kernel, dim3(MROWS), dim3(256), 0, stream, Gp, b1, g1, be1, Hbf);
  // W1T dead (H aliases it); G1 partials consumed -> Gp reused for GEMM2 partials
  {
    int nkb = N1DIM / 64;
    int kc = ((nkb + S2 - 1) / S2) * 64;              // 256
    int gy = FDIM / 128, nwg = 8 * gy * S2;           // 384
    hipLaunchKernelGGL(gemm_sk_kernel, dim3(nwg), dim3(256), 0, stream,
                       Hbf, w2t, Gp, MROWS, FDIM, N1DIM, kc, gy, nwg / 8);
  }
  hipLaunchKernelGGL(ln2_kernel, dim3(MROWS), dim3(256), 0, stream,
                     Gp, b2, g2, be2, miss, det, out);
}

// Round 6
// 189.926 us; speedup vs baseline: 5.6332x; 1.0054x over previous
//
#include <hip/hip_runtime.h>

typedef __bf16 bf16x8 __attribute__((ext_vector_type(8)));
typedef float f32x4 __attribute__((ext_vector_type(4)));
typedef unsigned short ushort8v __attribute__((ext_vector_type(8)));
typedef unsigned short ushort4v __attribute__((ext_vector_type(4)));

#define BATCH 32
#define NBOX 40
#define CCH 256
#define HF 64
#define WF 64
#define RREG 29
#define OUTP 7
#define MROWS 928           // BATCH*RREG
#define DDIM 12544          // CCH*7*7
#define N1DIM 2048
#define FDIM 768
#define PDIM 4096           // HF*WF
#define S1 8                // split-K factor GEMM1
#define S2 8                // split-K factor GEMM2

// ---- workspace layout (bytes), lifetime-aliased ----
static constexpr size_t OFF_ROIS = 0;                                   // 928*4 f32
static constexpr size_t OFF_DET  = 16384;                               // 928 i32
static constexpr size_t OFF_A    = 32768;                               // bf16 [928][12544]
static constexpr size_t OFF_W1T  = OFF_A   + (size_t)MROWS * DDIM * 2;  // bf16 [2048][12544]
static constexpr size_t OFF_FMT  = OFF_W1T;                             // bf16 [32][4096][256] (dead after roi)
static constexpr size_t OFF_W2T  = OFF_W1T + (size_t)DDIM * N1DIM * 2;  // bf16 [768][2048]
static constexpr size_t OFF_GP   = OFF_W2T + (size_t)N1DIM * FDIM * 2;  // f32 [S1][928][2048]; later [S2][928][768]
static constexpr size_t OFF_H    = OFF_W1T;                             // bf16 [928][2048] (W1T dead after gemm1)

static __device__ __forceinline__ unsigned short f2bf(float f) {
  __bf16 h = (__bf16)f;
  return __builtin_bit_cast(unsigned short, h);
}
static __device__ __forceinline__ float bf2f(unsigned short u) {
  unsigned int x = ((unsigned int)u) << 16;
  return __builtin_bit_cast(float, x);
}
static __device__ __forceinline__ void gload_lds16(const void* g, void* l) {
  __builtin_amdgcn_global_load_lds((const __attribute__((address_space(1))) void*)g,
                                   (__attribute__((address_space(3))) void*)l, 16, 0, 0);
}

// ---------------- 1. select (4 blocks) + fmt NCHW f32 -> NHWC bf16 (8192 blocks) ----
__global__ __launch_bounds__(256) void selfmt_kernel(const float* __restrict__ in,
                                                     unsigned short* __restrict__ out,
                                                     const float* __restrict__ boxes,
                                                     const float* __restrict__ scores,
                                                     const int* __restrict__ labels,
                                                     float* __restrict__ rois,
                                                     int* __restrict__ det,
                                                     float* __restrict__ out_det) {
  __shared__ float tile[64][65];
  int bid = blockIdx.x;
  int t = threadIdx.x;
  if (bid >= PDIM / 64 * (CCH / 64) * BATCH) {   // ---- select part (4 trailing blocks)
    int tid = (bid - PDIM / 64 * (CCH / 64) * BATCH) * 256 + t;
    if (tid >= MROWS) return;
    int b = tid / RREG, r = tid % RREG;
    float bestS = -1.0f;
    int bestN = 0;
    int found = 0;
    for (int n = 0; n < NBOX; ++n) {
      int lab = labels[b * NBOX + n];
      int ri = min(max(lab, 1), RREG) - 1;
      if (ri == r) {
        found = 1;
        float s = scores[b * NBOX + n];
        if (s > bestS) { bestS = s; bestN = n; }
      }
    }
    const float scale = 0.0625f;
    float4 bx = *(const float4*)&boxes[(b * NBOX + bestN) * 4];
    rois[tid * 4 + 0] = bx.x * scale;
    rois[tid * 4 + 1] = bx.y * scale;
    rois[tid * 4 + 2] = bx.z * scale;
    rois[tid * 4 + 3] = bx.w * scale;
    det[tid] = found;
    out_det[tid] = found ? 1.0f : 0.0f;
    return;
  }
  // ---- fmt part
  int p0 = (bid & 63) * 64, c0 = ((bid >> 6) & 3) * 64, b = bid >> 8;
  int tx = t & 15, ty = t >> 4;
#pragma unroll
  for (int q = 0; q < 4; ++q) {
    int r = ty + q * 16;
    float4 v = *(const float4*)&in[((long)b * CCH + c0 + r) * PDIM + p0 + tx * 4];
    tile[r][tx * 4 + 0] = v.x;
    tile[r][tx * 4 + 1] = v.y;
    tile[r][tx * 4 + 2] = v.z;
    tile[r][tx * 4 + 3] = v.w;
  }
  __syncthreads();
#pragma unroll
  for (int q = 0; q < 4; ++q) {
    int r = ty + q * 16;
    ushort4v o;
    o[0] = f2bf(tile[tx * 4 + 0][r]);
    o[1] = f2bf(tile[tx * 4 + 1][r]);
    o[2] = f2bf(tile[tx * 4 + 2][r]);
    o[3] = f2bf(tile[tx * 4 + 3][r]);
    *(ushort4v*)&out[((long)b * PDIM + p0 + r) * CCH + c0 + tx * 4] = o;
  }
}

// ---------------- 2. roi align (NHWC bf16) -> bf16 [928][12544] ----------------
__global__ __launch_bounds__(256) void roi_kernel(const unsigned short* __restrict__ fmT,
                                                  const float* __restrict__ rois,
                                                  unsigned short* __restrict__ A) {
  __shared__ int sidx[196][4];
  __shared__ float swt[196][4];
  __shared__ unsigned short Arow[DDIM];
  int roi = blockIdx.x;
  int t = threadIdx.x;
  float rx1 = rois[roi * 4 + 0], ry1 = rois[roi * 4 + 1];
  float rx2 = rois[roi * 4 + 2], ry2 = rois[roi * 4 + 3];
  float roiw = fmaxf(rx2 - rx1, 1.f), roih = fmaxf(ry2 - ry1, 1.f);
  float bw = roiw * (1.f / OUTP), bh = roih * (1.f / OUTP);
  if (t < 196) {
    int oy = t / 28, rem = t % 28, ox = rem / 4, s = rem % 4, sy = s >> 1, sx = s & 1;
    float y = ry1 + ((float)oy + ((float)sy + 0.5f) * 0.5f) * bh;
    float x = rx1 + ((float)ox + ((float)sx + 0.5f) * 0.5f) * bw;
    bool valid = (y >= -1.f) && (y <= 64.f) && (x >= -1.f) && (x <= 64.f);
    float yc = fminf(fmaxf(y, 0.f), 63.f);
    float xc = fminf(fmaxf(x, 0.f), 63.f);
    int y0 = (int)floorf(yc), x0 = (int)floorf(xc);
    int y1i = min(y0 + 1, 63), x1i = min(x0 + 1, 63);
    float ly = yc - (float)y0, lx = xc - (float)x0;
    float hy = 1.f - ly, hx = 1.f - lx;
    float m = valid ? 1.f : 0.f;
    swt[t][0] = hy * hx * m;
    swt[t][1] = hy * lx * m;
    swt[t][2] = ly * hx * m;
    swt[t][3] = ly * lx * m;
    sidx[t][0] = (y0 * 64 + x0) * CCH;
    sidx[t][1] = (y0 * 64 + x1i) * CCH;
    sidx[t][2] = (y1i * 64 + x0) * CCH;
    sidx[t][3] = (y1i * 64 + x1i) * CCH;
  }
  __syncthreads();
  int b = roi / RREG;
  int cg = t & 63;                       // 4 channels: cg*4 .. cg*4+3
  int sub = t >> 6;                      // bin subset
  int start = sub * 12 + min(sub, 1);    // 0,13,25,37
  int cnt = sub == 0 ? 13 : 12;
  const unsigned short* base = fmT + (long)b * PDIM * CCH + cg * 4;
  for (int bi = 0; bi < cnt; ++bi) {
    int bin = start + bi;
    float a0 = 0.f, a1 = 0.f, a2 = 0.f, a3 = 0.f;
#pragma unroll
    for (int s = 0; s < 4; ++s) {
      int sid = bin * 4 + s;
#pragma unroll
      for (int tp = 0; tp < 4; ++tp) {
        float w = swt[sid][tp];
        ushort4v v = *(const ushort4v*)(base + sidx[sid][tp]);
        a0 += w * bf2f(v[0]);
        a1 += w * bf2f(v[1]);
        a2 += w * bf2f(v[2]);
        a3 += w * bf2f(v[3]);
      }
    }
    Arow[(cg * 4 + 0) * 49 + bin] = f2bf(a0 * 0.25f);
    Arow[(cg * 4 + 1) * 49 + bin] = f2bf(a1 * 0.25f);
    Arow[(cg * 4 + 2) * 49 + bin] = f2bf(a2 * 0.25f);
    Arow[(cg * 4 + 3) * 49 + bin] = f2bf(a3 * 0.25f);
  }
  __syncthreads();
  const ushort8v* src = (const ushort8v*)Arow;
  ushort8v* dst = (ushort8v*)(A + (long)roi * DDIM);
  for (int i = t; i < DDIM / 8; i += 256) dst[i] = src[i];
}

// ---------------- 3. merged transpose f32 [K][N] -> bf16 [N][K] for w1 and w2 ------
// blocks [0, 6272): w1 (196 x 32 tiles); [6272, 6656): w2 (32 x 12 tiles)
__global__ __launch_bounds__(256) void wT_kernel(const float* __restrict__ w1,
                                                 unsigned short* __restrict__ w1t,
                                                 const float* __restrict__ w2,
                                                 unsigned short* __restrict__ w2t) {
  __shared__ float tile[64][65];
  int bid = blockIdx.x;
  const float* in;
  unsigned short* out;
  int K, N, k0, n0;
  if (bid < (DDIM / 64) * (N1DIM / 64)) {
    in = w1; out = w1t; K = DDIM; N = N1DIM;
    k0 = (bid % (DDIM / 64)) * 64;
    n0 = (bid / (DDIM / 64)) * 64;
  } else {
    int r = bid - (DDIM / 64) * (N1DIM / 64);
    in = w2; out = w2t; K = N1DIM; N = FDIM;
    k0 = (r % (N1DIM / 64)) * 64;
    n0 = (r / (N1DIM / 64)) * 64;
  }
  int t = threadIdx.x, tx = t & 15, ty = t >> 4;
#pragma unroll
  for (int p = 0; p < 4; ++p) {
    int r = ty + p * 16;
    float4 v = *(const float4*)&in[(long)(k0 + r) * N + n0 + tx * 4];
    tile[r][tx * 4 + 0] = v.x;
    tile[r][tx * 4 + 1] = v.y;
    tile[r][tx * 4 + 2] = v.z;
    tile[r][tx * 4 + 3] = v.w;
  }
  __syncthreads();
#pragma unroll
  for (int p = 0; p < 4; ++p) {
    int r = ty + p * 16;
    ushort4v o;
    o[0] = f2bf(tile[tx * 4 + 0][r]);
    o[1] = f2bf(tile[tx * 4 + 1][r]);
    o[2] = f2bf(tile[tx * 4 + 2][r]);
    o[3] = f2bf(tile[tx * 4 + 3][r]);
    *(ushort4v*)&out[(long)(n0 + r) * K + k0 + tx * 4] = o;
  }
}

// ---------------- 4. split-K bf16 MFMA GEMM, counted-vmcnt pipeline (T4) ----------
// 2-buffer double-buffered LDS; gloads stay in flight across raw barriers.
// Per thread per stage: exactly 8 global_load_lds. Ghost re-stages (clamped kt)
// keep outstanding==16 before each wait, so vmcnt(8) always waits for exactly
// the current tile's 8 loads. WAR safe: stage issued after the barrier proving
// all waves consumed that buffer.
__global__ __launch_bounds__(256, 2) void gemm_sk_kernel(const unsigned short* __restrict__ A,
                                                         const unsigned short* __restrict__ Bt,
                                                         float* __restrict__ Cp,
                                                         int M, int N, int K, int kchunk,
                                                         int gy, int q) {
  __shared__ unsigned short As[2 * 128 * 64];   // [buf][row][chunk^(row&7)] bf16
  __shared__ unsigned short Bs[2 * 128 * 64];
  int bid = blockIdx.x;
  int tile = (bid & 7) * q + (bid >> 3);    // bijective XCD-chunked swizzle (nwg % 8 == 0)
  int bm = tile & 7;
  int rest = tile >> 3;
  int bn = rest % gy;
  int s = rest / gy;

  int t = threadIdx.x;
  int lane = t & 63, wv = t >> 6;
  int wr = wv >> 1, wc = wv & 1;
  int fr = lane & 15, fq = lane >> 4;

  f32x4 acc[4][4];
#pragma unroll
  for (int m = 0; m < 4; ++m)
#pragma unroll
    for (int n = 0; n < 4; ++n) acc[m][n] = (f32x4){0.f, 0.f, 0.f, 0.f};

  int srow = t >> 3;
  int scol = t & 7;
  int k_begin = s * kchunk;
  int k_end = min(k_begin + kchunk, K);     // BK-aligned split boundaries
  int nkt = (k_end - k_begin) >> 6;         // number of 64-wide K-tiles

  int garow[4], gbrow[4], schunk[4];
#pragma unroll
  for (int i = 0; i < 4; ++i) {
    int row = srow + i * 32;
    schunk[i] = (scol ^ (row & 7)) * 8;
    garow[i] = min(bm * 128 + row, M - 1);
    gbrow[i] = bn * 128 + row;
  }

#define GSTAGE(buf, kt_) do {                                                  \
    int k0_ = k_begin + (kt_) * 64;                                            \
    _Pragma("unroll")                                                          \
    for (int i = 0; i < 4; ++i)                                                \
      gload_lds16(A + (long)garow[i] * K + k0_ + schunk[i],                    \
                  (char*)As + (buf) * 16384 + t * 16 + i * 4096);              \
    _Pragma("unroll")                                                          \
    for (int i = 0; i < 4; ++i)                                                \
      gload_lds16(Bt + (long)gbrow[i] * K + k0_ + schunk[i],                   \
                  (char*)Bs + (buf) * 16384 + t * 16 + i * 4096);              \
  } while (0)

  // prologue: 16 loads in flight
  GSTAGE(0, 0);
  GSTAGE(1, min(1, nkt - 1));

  for (int kt = 0; kt < nkt; ++kt) {
    int cur = kt & 1;
    asm volatile("s_waitcnt vmcnt(8)" ::: "memory");   // own tile-kt loads landed
    __builtin_amdgcn_sched_barrier(0);
    __builtin_amdgcn_s_barrier();                      // => all waves' loads landed
    __builtin_amdgcn_sched_barrier(0);

    const char* Ab = (const char*)As + cur * 16384;
    const char* Bb = (const char*)Bs + cur * 16384;
#pragma unroll
    for (int ks = 0; ks < 2; ++ks) {
      bf16x8 af[4], bfv[4];
#pragma unroll
      for (int m = 0; m < 4; ++m) {
        int row = wr * 64 + m * 16 + fr;
        int bc = (ks * 64 + fq * 16) ^ ((row & 7) << 4);
        af[m] = *(const bf16x8*)(Ab + row * 128 + bc);
      }
#pragma unroll
      for (int n = 0; n < 4; ++n) {
        int row = wc * 64 + n * 16 + fr;
        int bc = (ks * 64 + fq * 16) ^ ((row & 7) << 4);
        bfv[n] = *(const bf16x8*)(Bb + row * 128 + bc);
      }
#pragma unroll
      for (int m = 0; m < 4; ++m)
#pragma unroll
        for (int n = 0; n < 4; ++n)
          acc[m][n] = __builtin_amdgcn_mfma_f32_16x16x32_bf16(af[m], bfv[n], acc[m][n], 0, 0, 0);
    }

    __builtin_amdgcn_sched_barrier(0);
    __builtin_amdgcn_s_barrier();                      // all waves done reading buf cur
    __builtin_amdgcn_sched_barrier(0);
    GSTAGE(cur, min(kt + 2, nkt - 1));                 // re-stage (ghost when kt+2>=nkt)
  }
#undef GSTAGE

  float* Cb = Cp + (long)s * M * N;
#pragma unroll
  for (int m = 0; m < 4; ++m)
#pragma unroll
    for (int n = 0; n < 4; ++n) {
      int col = bn * 128 + wc * 64 + n * 16 + fr;
#pragma unroll
      for (int j = 0; j < 4; ++j) {
        int row = bm * 128 + wr * 64 + m * 16 + fq * 4 + j;
        if (row < M) Cb[(long)row * N + col] = acc[m][n][j];
      }
    }
}

// ---------------- block reduce helper ----------------
static __device__ __forceinline__ void block_reduce2(float& a, float& b, float* sm) {
#pragma unroll
  for (int off = 32; off > 0; off >>= 1) {
    a += __shfl_down(a, off);
    b += __shfl_down(b, off);
  }
  int lane = threadIdx.x & 63, wv = threadIdx.x >> 6;
  if (lane == 0) { sm[wv] = a; sm[wv + 4] = b; }
  __syncthreads();
  a = sm[0] + sm[1] + sm[2] + sm[3];
  b = sm[4] + sm[5] + sm[6] + sm[7];
}

// ---------------- 5. partial-sum + bias + LN + ReLU -> bf16 h ----------------
__global__ __launch_bounds__(256) void ln1_kernel(const float* __restrict__ X,
                                                  const float* __restrict__ b1,
                                                  const float* __restrict__ g1,
                                                  const float* __restrict__ be1,
                                                  unsigned short* __restrict__ H) {
  __shared__ float sm[8];
  int row = blockIdx.x, t = threadIdx.x;
  float x[8];
  float sum = 0.f, sq = 0.f;
#pragma unroll
  for (int i = 0; i < 8; ++i) {
    int j = t + i * 256;
    float v = b1[j];
#pragma unroll
    for (int s = 0; s < S1; ++s) v += X[((long)s * MROWS + row) * N1DIM + j];
    x[i] = v;
    sum += v;
    sq += v * v;
  }
  block_reduce2(sum, sq, sm);
  float mu = sum * (1.f / N1DIM);
  float inv = rsqrtf(sq * (1.f / N1DIM) - mu * mu + 1e-5f);
#pragma unroll
  for (int i = 0; i < 8; ++i) {
    int j = t + i * 256;
    float y = fmaxf((x[i] - mu) * inv * g1[j] + be1[j], 0.f);
    H[(long)row * N1DIM + j] = f2bf(y);
  }
}

// ---------------- 6. partial-sum + bias + LN + missing-token -> out ----------------
__global__ __launch_bounds__(256) void ln2_kernel(const float* __restrict__ X,
                                                  const float* __restrict__ b2,
                                                  const float* __restrict__ g2,
                                                  const float* __restrict__ be2,
                                                  const float* __restrict__ miss,
                                                  const int* __restrict__ det,
                                                  float* __restrict__ out) {
  __shared__ float sm[8];
  int row = blockIdx.x, t = threadIdx.x;
  float x[3];
  float sum = 0.f, sq = 0.f;
#pragma unroll
  for (int i = 0; i < 3; ++i) {
    int j = t + i * 256;
    float v = b2[j];
#pragma unroll
    for (int s = 0; s < S2; ++s) v += X[((long)s * MROWS + row) * FDIM + j];
    x[i] = v;
    sum += v;
    sq += v * v;
  }
  block_reduce2(sum, sq, sm);
  float mu = sum * (1.f / FDIM);
  float inv = rsqrtf(sq * (1.f / FDIM) - mu * mu + 1e-5f);
  int dv = det[row];
#pragma unroll
  for (int i = 0; i < 3; ++i) {
    int j = t + i * 256;
    float y = (x[i] - mu) * inv * g2[j] + be2[j];
    out[(long)row * FDIM + j] = dv ? y : miss[j];
  }
}

extern "C" void kernel_launch(void* const* d_in, const int* in_sizes, int n_in,
                              void* d_out, int out_size, void* d_ws, size_t ws_size,
                              hipStream_t stream) {
  const float* fm     = (const float*)d_in[0];
  const float* boxes  = (const float*)d_in[1];
  const float* scores = (const float*)d_in[2];
  const int*   labels = (const int*)d_in[3];
  const float* w1     = (const float*)d_in[4];
  const float* b1     = (const float*)d_in[5];
  const float* g1     = (const float*)d_in[6];
  const float* be1    = (const float*)d_in[7];
  const float* w2     = (const float*)d_in[8];
  const float* b2     = (const float*)d_in[9];
  const float* g2     = (const float*)d_in[10];
  const float* be2    = (const float*)d_in[11];
  const float* miss   = (const float*)d_in[12];
  float* out = (float*)d_out;
  char* ws = (char*)d_ws;

  float* rois = (float*)(ws + OFF_ROIS);
  int* det = (int*)(ws + OFF_DET);
  unsigned short* Abf = (unsigned short*)(ws + OFF_A);
  unsigned short* fmT = (unsigned short*)(ws + OFF_FMT);
  unsigned short* w1t = (unsigned short*)(ws + OFF_W1T);
  unsigned short* w2t = (unsigned short*)(ws + OFF_W2T);
  float* Gp = (float*)(ws + OFF_GP);
  unsigned short* Hbf = (unsigned short*)(ws + OFF_H);

  // select (4 blocks) + fmt (8192 blocks)
  hipLaunchKernelGGL(selfmt_kernel, dim3(8192 + 4), dim3(256), 0, stream,
                     fm, fmT, boxes, scores, labels, rois, det, out + (long)MROWS * FDIM);
  hipLaunchKernelGGL(roi_kernel, dim3(MROWS), dim3(256), 0, stream, fmT, rois, Abf);
  // fmT dead; w1t/w2t overwrite its region (stream-ordered)
  hipLaunchKernelGGL(wT_kernel, dim3((DDIM / 64) * (N1DIM / 64) + (N1DIM / 64) * (FDIM / 64)),
                     dim3(256), 0, stream, w1, w1t, w2, w2t);
  {
    // GEMM1: 196 k-blocks; kchunk = ceil(196/S1)*64 = 1600 (s=7 takes 1344)
    int nkb = DDIM / 64;
    int kc = ((nkb + S1 - 1) / S1) * 64;
    int gy = N1DIM / 128, nwg = 8 * gy * S1;          // 1024
    hipLaunchKernelGGL(gemm_sk_kernel, dim3(nwg), dim3(256), 0, stream,
                       Abf, w1t, Gp, MROWS, N1DIM, DDIM, kc, gy, nwg / 8);
  }
  hipLaunchKernelGGL(ln1_kernel, dim3(MROWS), dim3(256), 0, stream, Gp, b1, g1, be1, Hbf);
  // W1T dead (H aliases it); G1 partials consumed -> Gp reused for GEMM2 partials
  {
    int nkb = N1DIM / 64;
    int kc = ((nkb + S2 - 1) / S2) * 64;              // 256
    int gy = FDIM / 128, nwg = 8 * gy * S2;           // 384
    hipLaunchKernelGGL(gemm_sk_kernel, dim3(nwg), dim3(256), 0, stream,
                       Hbf, w2t, Gp, MROWS, FDIM, N1DIM, kc, gy, nwg / 8);
  }
  hipLaunchKernelGGL(ln2_kernel, dim3(MROWS), dim3(256), 0, stream,
                     Gp, b2, g2, be2, miss, det, out);
}